// Round 6
// baseline (33309.671 us; speedup 1.0000x reference)
//
#include <hip/hip_runtime.h>
#include <hip/hip_bf16.h>
#include <cstdint>
#include <cstddef>

#define S_LEN 512
#define B_SZ  512
#define T_LEN 160
#define E_DIM 256
#define H_DIM 512
#define V_DIM 34
#define G4    2048          // 4*H
#define XROW  768           // [h1 (512) | ctx (256)] history row
#define EPS1  1e-12f
#define BE    (B_SZ * E_DIM)

typedef unsigned short u16;
typedef __attribute__((ext_vector_type(8))) short bf16x8;
typedef __attribute__((ext_vector_type(4))) float f32x4;

#define SMEM_BYTES 18432    // 2*64*72*2 staging / 64*68*4 C-tile

// ---------------- helpers ----------------
__device__ __forceinline__ float wave_reduce_sum(float v) {
#pragma unroll
  for (int m = 32; m >= 1; m >>= 1) v += __shfl_xor(v, m, 64);
  return v;
}
__device__ __forceinline__ float half_reduce_sum(float v) {  // within 32-lane group
#pragma unroll
  for (int m = 16; m >= 1; m >>= 1) v += __shfl_xor(v, m, 64);
  return v;
}
__device__ __forceinline__ float wave_reduce_max(float v) {
#pragma unroll
  for (int m = 32; m >= 1; m >>= 1) v = fmaxf(v, __shfl_xor(v, m, 64));
  return v;
}
__device__ __forceinline__ float bf2f(u16 u) {
  return __uint_as_float((uint32_t)u << 16);
}
__device__ __forceinline__ float4 load4(const float* p) { return *(const float4*)p; }
__device__ __forceinline__ float4 load4(const u16* p) {
  ushort4 u = *(const ushort4*)p;
  float4 r;
  r.x = bf2f(u.x); r.y = bf2f(u.y); r.z = bf2f(u.z); r.w = bf2f(u.w);
  return r;
}
__device__ __forceinline__ float dot8(const u16* p, const float* q) {
  bf16x8 k8 = *(const bf16x8*)p;
  float acc = 0.f;
#pragma unroll
  for (int i = 0; i < 8; ++i) acc += bf2f((u16)k8[i]) * q[i];
  return acc;
}
__device__ __forceinline__ float dot8(const float* p, const float* q) {
  float4 a = *(const float4*)p, b = *(const float4*)(p + 4);
  return a.x*q[0] + a.y*q[1] + a.z*q[2] + a.w*q[3] +
         b.x*q[4] + b.y*q[5] + b.z*q[6] + b.w*q[7];
}
__device__ __forceinline__ u16 f2bf(float f) {
  uint32_t u = __float_as_uint(f);
  uint32_t r = (u + 0x7FFFu + ((u >> 16) & 1u)) >> 16;
  return (u16)r;
}
__device__ __forceinline__ float sigm(float x) { return 1.f / (1.f + __expf(-x)); }

// ---------------- generic MFMA tile accumulate ----------------
// acc += A[m0..m0+63, 0..klen) . W[n0..n0+63, 0..klen)^T
__device__ __forceinline__ void mfma_acc(const u16* A, int lda, const u16* W, int ldw,
                                         int klen, int m0, int n0, char* smem,
                                         f32x4 (&acc)[2][2]) {
  u16 (*As)[72] = (u16(*)[72])smem;
  u16 (*Ws)[72] = (u16(*)[72])(smem + 64 * 72 * 2);
  const int tid = threadIdx.x;
  const int lane = tid & 63, wave = tid >> 6;
  const int wm = (wave >> 1) * 32, wn = (wave & 1) * 32;
  const int row = lane & 15, kq = (lane >> 4) * 8;

  for (int k0 = 0; k0 < klen; k0 += 64) {
    __syncthreads();
#pragma unroll
    for (int i = tid; i < 512; i += 256) {
      int r = i >> 3, c = (i & 7) * 8;
      *(bf16x8*)&As[r][c] = *(const bf16x8*)(A + (size_t)(m0 + r) * lda + k0 + c);
      *(bf16x8*)&Ws[r][c] = *(const bf16x8*)(W + (size_t)(n0 + r) * ldw + k0 + c);
    }
    __syncthreads();
#pragma unroll
    for (int kk = 0; kk < 64; kk += 32) {
      bf16x8 a0 = *(const bf16x8*)&As[wm + row][kk + kq];
      bf16x8 a1 = *(const bf16x8*)&As[wm + 16 + row][kk + kq];
      bf16x8 b0 = *(const bf16x8*)&Ws[wn + row][kk + kq];
      bf16x8 b1 = *(const bf16x8*)&Ws[wn + 16 + row][kk + kq];
      acc[0][0] = __builtin_amdgcn_mfma_f32_16x16x32_bf16(a0, b0, acc[0][0], 0, 0, 0);
      acc[0][1] = __builtin_amdgcn_mfma_f32_16x16x32_bf16(a0, b1, acc[0][1], 0, 0, 0);
      acc[1][0] = __builtin_amdgcn_mfma_f32_16x16x32_bf16(a1, b0, acc[1][0], 0, 0, 0);
      acc[1][1] = __builtin_amdgcn_mfma_f32_16x16x32_bf16(a1, b1, acc[1][1], 0, 0, 0);
    }
  }
}

// LSTM epilogue: Cs = acc + pg + bias -> gates -> h, c
__device__ __forceinline__ void cell_epilogue(f32x4 (&acc)[2][2], int m0, int n0,
                                              const float* __restrict__ pg,
                                              const float* __restrict__ biasp,
                                              float* __restrict__ cbuf,
                                              u16* __restrict__ hb,
                                              u16* __restrict__ xh, char* smem) {
  const int tid = threadIdx.x;
  const int lane = tid & 63, wave = tid >> 6;
  __syncthreads();
  float (*Cs)[68] = (float(*)[68])smem;
  const int wm = (wave >> 1) * 32, wn = (wave & 1) * 32;
  const int col = lane & 15, r4 = (lane >> 4) * 4;
#pragma unroll
  for (int fm = 0; fm < 2; ++fm)
#pragma unroll
    for (int fn = 0; fn < 2; ++fn) {
      int cc = wn + fn * 16 + col;
      float bias = biasp[n0 + cc];
#pragma unroll
      for (int r = 0; r < 4; ++r) {
        int rr = wm + fm * 16 + r4 + r;
        Cs[rr][cc] = acc[fm][fn][r] + pg[(size_t)(m0 + rr) * G4 + n0 + cc] + bias;
      }
    }
  __syncthreads();
  for (int i = tid; i < 1024; i += 256) {
    int m = i >> 4, j = i & 15;
    float4 gv = *(const float4*)&Cs[m][j * 4];   // i,f,g,o
    float ii = sigm(gv.x), ff = sigm(gv.y), tg = tanhf(gv.z), oo = sigm(gv.w);
    int gm = m0 + m, gj = (n0 >> 2) + j;
    size_t cidx = (size_t)gm * H_DIM + gj;
    float cn = ff * cbuf[cidx] + ii * tg;
    float hn = oo * tanhf(cn);
    cbuf[cidx] = cn;
    u16 hv = f2bf(hn);
    hb[cidx] = hv;
    if (xh) xh[(size_t)gm * XROW + gj] = hv;
  }
}

// ---------------- init ----------------
__global__ __launch_bounds__(256)
void init_state(const float* __restrict__ s0, const float* __restrict__ s1,
                const float* __restrict__ cs0, const float* __restrict__ cs1,
                u16* __restrict__ h0b, u16* __restrict__ h1b,
                float* __restrict__ c0, float* __restrict__ c1) {
  int idx = blockIdx.x * blockDim.x + threadIdx.x;  // < B*H
  int j = idx & 511;
  h0b[idx] = f2bf(s0[j]);
  h1b[idx] = f2bf(s1[j]);
  c0[idx] = cs0[j];
  c1[idx] = cs1[j];
}

__global__ __launch_bounds__(64)
void zero_cnts(int* __restrict__ c) {
  if (threadIdx.x < 16) c[threadIdx.x] = 0;
}

// ---------------- fp32 -> bf16 (K/V) ----------------
__global__ __launch_bounds__(256)
void conv_bf16(const float* __restrict__ in, u16* __restrict__ outp, int n4) {
  int i = blockIdx.x * blockDim.x + threadIdx.x;
  int stride = gridDim.x * blockDim.x;
  for (; i < n4; i += stride) {
    float4 f = ((const float4*)in)[i];
    ushort4 u;
    u.x = f2bf(f.x); u.y = f2bf(f.y); u.z = f2bf(f.z); u.w = f2bf(f.w);
    ((ushort4*)outp)[i] = u;
  }
}

// ---------------- weight packs ----------------
__global__ __launch_bounds__(256)
void pack_w(const float* __restrict__ in, u16* __restrict__ outp) {
  int idx = blockIdx.x * 256 + threadIdx.x;   // 2048*64
  int k = (idx & 63) * 8;
  int np = idx >> 6;
  int j = np >> 2, g = np & 3;
  const float* src = in + ((size_t)(g * 512 + j)) * 512 + k;
  float4 f0 = *(const float4*)src;
  float4 f1 = *(const float4*)(src + 4);
  ushort4 o0, o1;
  o0.x = f2bf(f0.x); o0.y = f2bf(f0.y); o0.z = f2bf(f0.z); o0.w = f2bf(f0.w);
  o1.x = f2bf(f1.x); o1.y = f2bf(f1.y); o1.z = f2bf(f1.z); o1.w = f2bf(f1.w);
  *(ushort4*)(outp + (size_t)np * 512 + k) = o0;
  *(ushort4*)(outp + (size_t)np * 512 + k + 4) = o1;
}

__global__ __launch_bounds__(256)
void pack_wq(const float* __restrict__ in, u16* __restrict__ outp) {
  int idx = blockIdx.x * 256 + threadIdx.x;   // 256*64
  int k = (idx & 63) * 8;
  int e = idx >> 6;
  const float* src = in + (size_t)e * 512 + k;
  float4 f0 = *(const float4*)src;
  float4 f1 = *(const float4*)(src + 4);
  ushort4 o0, o1;
  o0.x = f2bf(f0.x); o0.y = f2bf(f0.y); o0.z = f2bf(f0.z); o0.w = f2bf(f0.w);
  o1.x = f2bf(f1.x); o1.y = f2bf(f1.y); o1.z = f2bf(f1.z); o1.w = f2bf(f1.w);
  *(ushort4*)(outp + (size_t)e * 512 + k) = o0;
  *(ushort4*)(outp + (size_t)e * 512 + k + 4) = o1;
}

// Wscb: 64 rows x 768 cols, rows >= V_DIM zeroed
__global__ __launch_bounds__(256)
void pack_wsc(const float* __restrict__ in, u16* __restrict__ outp) {
  int idx = blockIdx.x * 256 + threadIdx.x;   // 64*96 = 6144
  if (idx >= 64 * 96) return;
  int kq = (idx % 96) * 8;
  int v = idx / 96;
  ushort4 o0 = {0, 0, 0, 0}, o1 = {0, 0, 0, 0};
  if (v < V_DIM) {
    const float* src = in + (size_t)v * XROW + kq;
    float4 f0 = *(const float4*)src;
    float4 f1 = *(const float4*)(src + 4);
    o0.x = f2bf(f0.x); o0.y = f2bf(f0.y); o0.z = f2bf(f0.z); o0.w = f2bf(f0.w);
    o1.x = f2bf(f1.x); o1.y = f2bf(f1.y); o1.z = f2bf(f1.z); o1.w = f2bf(f1.w);
  }
  *(ushort4*)(outp + (size_t)v * XROW + kq) = o0;
  *(ushort4*)(outp + (size_t)v * XROW + kq + 4) = o1;
}

__global__ __launch_bounds__(256)
void pack_bias(const float* bih0, const float* bhh0,
               const float* bih1, const float* bhh1,
               float* bias0p, float* bias1p) {
  int np = blockIdx.x * 256 + threadIdx.x;  // < 2048
  int j = np >> 2, g = np & 3;
  int n = g * 512 + j;
  bias0p[np] = bih0[n] + bhh0[n];
  bias1p[np] = bih1[n] + bhh1[n];
}

// ---------------- pre-gather all embeddings (bf16) ----------------
__global__ __launch_bounds__(256)
void gather_embs(const float* __restrict__ Emb, const int* __restrict__ labels,
                 u16* __restrict__ embs) {
  int idx = blockIdx.x * 256 + threadIdx.x;   // < T*B*64 quads
  if (idx >= T_LEN * B_SZ * 64) return;
  int q = idx & 63;
  int b = (idx >> 6) & 511;
  int t = idx >> 15;
  int lab = labels[(size_t)b * T_LEN + t];
  float4 f = *(const float4*)(Emb + (size_t)lab * E_DIM + q * 4);
  ushort4 o;
  o.x = f2bf(f.x); o.y = f2bf(f.y); o.z = f2bf(f.z); o.w = f2bf(f.w);
  *(ushort4*)(embs + ((size_t)t * B_SZ + b) * E_DIM + q * 4) = o;
}

// ---------------- standalone q GEMM (initial q only) ----------------
__global__ __launch_bounds__(256)
void qgemm(const u16* __restrict__ h1b, const u16* __restrict__ Wqb,
           const float* __restrict__ bq, float* __restrict__ qbuf) {
  __shared__ char smem[SMEM_BYTES];
  const int lane = threadIdx.x & 63, wave = threadIdx.x >> 6;
  const int m0 = blockIdx.y * 64, n0 = blockIdx.x * 64;
  f32x4 acc[2][2] = {};
  mfma_acc(h1b, H_DIM, Wqb, 512, 512, m0, n0, smem, acc);
  const int wm = (wave >> 1) * 32, wn = (wave & 1) * 32;
  const int col = lane & 15, r4 = (lane >> 4) * 4;
#pragma unroll
  for (int fm = 0; fm < 2; ++fm)
#pragma unroll
    for (int fn = 0; fn < 2; ++fn) {
      int cc = n0 + wn + fn * 16 + col;
      float bias = bq[cc];
#pragma unroll
      for (int r = 0; r < 4; ++r) {
        int rr = m0 + wm + fm * 16 + r4 + r;
        qbuf[(size_t)rr * E_DIM + cc] = acc[fm][fn][r] + bias;
      }
    }
}

// ---------------- kernel A: two-phase attend (blocks 0..511) + partial GEMMs --
template <typename KVT, bool DEFER>
__global__ __launch_bounds__(256)
void fusedA(const KVT* __restrict__ key, const KVT* __restrict__ value,
            const float* __restrict__ mask, const float* __restrict__ qbuf,
            const float* __restrict__ Wsc, const float* __restrict__ bsc,
            const u16* __restrict__ embs,
            const u16* __restrict__ h0b, const u16* __restrict__ h1b,
            const u16* __restrict__ Wih0p, const u16* __restrict__ Whh0p,
            const u16* __restrict__ Whh1p,
            u16* __restrict__ xc0, u16* __restrict__ xhist,
            float* __restrict__ pg0, float* __restrict__ pg1,
            float* __restrict__ out, int t) {
  __shared__ char smem[SMEM_BYTES];
  const int tid = threadIdx.x;
  const int lane = tid & 63;
  const int wave = tid >> 6;

  if (blockIdx.x >= 512) {
    // -------- partial gate GEMM --------
    if (t >= T_LEN) return;
    int gb = blockIdx.x - 512;
    int m0 = ((gb & 255) >> 5) * 64, n0 = (gb & 31) * 64;
    f32x4 acc[2][2] = {};
    float* pg;
    if (gb < 256) {
      mfma_acc(h0b, H_DIM, Whh0p, 512, 512, m0, n0, smem, acc);
      mfma_acc(embs + (size_t)t * BE, E_DIM, Wih0p, 512, 256, m0, n0, smem, acc);
      pg = pg0;
    } else {
      mfma_acc(h1b, H_DIM, Whh1p, 512, 512, m0, n0, smem, acc);
      pg = pg1;
    }
    const int wm = (wave >> 1) * 32, wn = (wave & 1) * 32;
    const int col = lane & 15, r4 = (lane >> 4) * 4;
#pragma unroll
    for (int fm = 0; fm < 2; ++fm)
#pragma unroll
      for (int fn = 0; fn < 2; ++fn) {
        int cc = n0 + wn + fn * 16 + col;
#pragma unroll
        for (int r = 0; r < 4; ++r) {
          int rr = m0 + wm + fm * 16 + r4 + r;
          pg[(size_t)rr * G4 + cc] = acc[fm][fn][r];
        }
      }
    return;
  }

  // -------- attend (two-phase, independent iterations) --------
  float* qs   = (float*)smem;          // 256
  float* scb  = qs + 256;              // 512
  float* ctxs = scb + 512;             // 256
  float* ctxp = ctxs + 256;            // 4*256
  float* red  = ctxp + 1024;           // 8
  float* h1s  = red + 8;               // 512 (fallback scoring only)
  const int b = blockIdx.x;

  qs[tid] = qbuf[(size_t)b * E_DIM + tid];
  if (!DEFER) {
#pragma unroll
    for (int j = tid; j < H_DIM; j += 256) h1s[j] = bf2f(h1b[(size_t)b * H_DIM + j]);
  }
  __syncthreads();

  // scores: 2 s-rows per wave-iteration, 16B/lane K loads
  {
    int e0 = (lane & 31) << 3;
    float q8[8];
    *(float4*)&q8[0] = *(const float4*)&qs[e0];
    *(float4*)&q8[4] = *(const float4*)&qs[e0 + 4];
    int s = wave * 2 + (lane >> 5);
    const KVT* kp = key + (size_t)s * BE + (size_t)b * E_DIM + e0;
#pragma unroll 4
    for (; s < S_LEN; s += 8) {
      float acc = dot8(kp, q8);
      acc = half_reduce_sum(acc);
      if ((lane & 31) == 0) scb[s] = acc;
      kp += (size_t)8 * BE;
    }
  }
  __syncthreads();

  // masked softmax + renorm
  float v0 = scb[tid], v1 = scb[tid + 256];
  {
    float lm = wave_reduce_max(fmaxf(v0, v1));
    if (lane == 0) red[wave] = lm;
  }
  __syncthreads();
  float smax = fmaxf(fmaxf(red[0], red[1]), fmaxf(red[2], red[3]));
  __syncthreads();
  float m0 = mask[(size_t)b * S_LEN + tid];
  float m1 = mask[(size_t)b * S_LEN + tid + 256];
  float p0 = __expf(v0 - smax), p1 = __expf(v1 - smax);
  float pm0 = p0 * m0, pm1 = p1 * m1;
  {
    float sP = wave_reduce_sum(p0 + p1);
    float sPM = wave_reduce_sum(pm0 + pm1);
    if (lane == 0) { red[wave] = sP; red[4 + wave] = sPM; }
  }
  __syncthreads();
  float P  = red[0] + red[1] + red[2] + red[3];
  float PM = red[4] + red[5] + red[6] + red[7];
  float inv = 1.f / fmaxf(PM, EPS1 * P);
  scb[tid] = pm0 * inv;
  scb[tid + 256] = pm1 * inv;
  __syncthreads();

  // ctx: lane owns e-quad, waves split s 4-way; cross-wave reduce in LDS
  {
    float4 cacc = {0.f, 0.f, 0.f, 0.f};
    const KVT* vp = value + (size_t)wave * BE + (size_t)b * E_DIM + (lane << 2);
#pragma unroll 8
    for (int s = wave; s < S_LEN; s += 4) {
      float a = scb[s];
      float4 v4 = load4(vp);
      cacc.x += a * v4.x; cacc.y += a * v4.y; cacc.z += a * v4.z; cacc.w += a * v4.w;
      vp += (size_t)4 * BE;
    }
    *(float4*)&ctxp[wave * 256 + (lane << 2)] = cacc;
  }
  __syncthreads();
  {
    float ctxe = ctxp[tid] + ctxp[256 + tid] + ctxp[512 + tid] + ctxp[768 + tid];
    ctxs[tid] = ctxe;
    u16 cb = f2bf(ctxe);
    if (t < T_LEN) xc0[(size_t)b * E_DIM + tid] = cb;
    if (DEFER && t >= 1) xhist[((size_t)t * B_SZ + b) * XROW + H_DIM + tid] = cb;
  }

  if (!DEFER) {
    __syncthreads();
    if (t >= 1) {
      for (int v = wave; v < V_DIM; v += 4) {
        const float4* wr = reinterpret_cast<const float4*>(Wsc + (size_t)v * XROW);
        float4 w0 = wr[lane];
        float4 w1 = wr[lane + 64];
        float4 w2 = wr[lane + 128];
        const float* ha = &h1s[4 * lane];
        const float* hb = &h1s[256 + 4 * lane];
        const float* cx = &ctxs[4 * lane];
        float acc = w0.x * ha[0] + w0.y * ha[1] + w0.z * ha[2] + w0.w * ha[3] +
                    w1.x * hb[0] + w1.y * hb[1] + w1.z * hb[2] + w1.w * hb[3] +
                    w2.x * cx[0] + w2.y * cx[1] + w2.z * cx[2] + w2.w * cx[3];
        acc = wave_reduce_sum(acc);
        if (lane == 0) out[((size_t)b * T_LEN + (t - 1)) * V_DIM + v] = acc + bsc[v];
      }
    }
  }
}

// ---------------- fused cells: cell0 -> cell1 -> qgemm via agent-scope flags --
// blocks 0..255: cell0 ; 256..511: cell1 ; 512..543: q GEMM
// cnt[0..7]: cell0 m-tile counters ; cnt[8..15]: cell1 m-tile counters
__global__ __launch_bounds__(256)
void cells_kernel(const u16* __restrict__ xc0, const u16* __restrict__ Wih0p,
                  const float* __restrict__ pg0, const float* __restrict__ bias0p,
                  float* __restrict__ c0,
                  const u16* __restrict__ Wih1p,
                  const float* __restrict__ pg1, const float* __restrict__ bias1p,
                  float* __restrict__ c1,
                  const u16* __restrict__ Wqb, const float* __restrict__ bq,
                  float* __restrict__ qbuf,
                  u16* __restrict__ h0b, u16* __restrict__ h1b,
                  u16* __restrict__ xh, int* __restrict__ cnt, int t) {
  __shared__ char smem[SMEM_BYTES];
  const int tid = threadIdx.x;
  const int target = (t + 1) * 32;
  int blk = blockIdx.x;

  if (blk < 256) {
    // ---- cell0: gates = xc0 @ Wih0p[:,256:]^T + pg0 + bias ----
    const int m0 = (blk >> 5) * 64, n0 = (blk & 31) * 64;
    f32x4 acc[2][2] = {};
    mfma_acc(xc0, E_DIM, Wih0p + 256, 512, 256, m0, n0, smem, acc);
    cell_epilogue(acc, m0, n0, pg0, bias0p, c0, h0b, nullptr, smem);
    __threadfence();
    __syncthreads();
    if (tid == 0)
      __hip_atomic_fetch_add(&cnt[m0 >> 6], 1, __ATOMIC_RELEASE, __HIP_MEMORY_SCOPE_AGENT);
  } else if (blk < 512) {
    // ---- cell1: gates = h0 @ Wih1p^T + pg1 + bias ----
    blk -= 256;
    const int m0 = (blk >> 5) * 64, n0 = (blk & 31) * 64;
    if (tid == 0) {
      while (__hip_atomic_load(&cnt[m0 >> 6], __ATOMIC_ACQUIRE, __HIP_MEMORY_SCOPE_AGENT) < target)
        __builtin_amdgcn_s_sleep(2);
    }
    __syncthreads();
    f32x4 acc[2][2] = {};
    mfma_acc(h0b, H_DIM, Wih1p, 512, 512, m0, n0, smem, acc);
    cell_epilogue(acc, m0, n0, pg1, bias1p, c1, h1b, xh, smem);
    __threadfence();
    __syncthreads();
    if (tid == 0)
      __hip_atomic_fetch_add(&cnt[8 + (m0 >> 6)], 1, __ATOMIC_RELEASE, __HIP_MEMORY_SCOPE_AGENT);
  } else {
    // ---- q GEMM for next step: qbuf = h1 @ Wqb^T + bq ----
    blk -= 512;
    const int m0 = (blk >> 2) * 64, n0 = (blk & 3) * 64;
    if (tid == 0) {
      while (__hip_atomic_load(&cnt[8 + (m0 >> 6)], __ATOMIC_ACQUIRE, __HIP_MEMORY_SCOPE_AGENT) < target)
        __builtin_amdgcn_s_sleep(2);
    }
    __syncthreads();
    f32x4 acc[2][2] = {};
    mfma_acc(h1b, H_DIM, Wqb, 512, 512, m0, n0, smem, acc);
    const int lane = tid & 63, wave = tid >> 6;
    const int wm = (wave >> 1) * 32, wn = (wave & 1) * 32;
    const int col = lane & 15, r4 = (lane >> 4) * 4;
#pragma unroll
    for (int fm = 0; fm < 2; ++fm)
#pragma unroll
      for (int fn = 0; fn < 2; ++fn) {
        int cc = n0 + wn + fn * 16 + col;
        float bias = bq[cc];
#pragma unroll
        for (int r = 0; r < 4; ++r) {
          int rr = m0 + wm + fm * 16 + r4 + r;
          qbuf[(size_t)rr * E_DIM + cc] = acc[fm][fn][r] + bias;
        }
      }
  }
}

// ---------------- deferred scoring: out = xhist @ Wscb^T + bsc ----------------
__global__ __launch_bounds__(256)
void score_kernel(const u16* __restrict__ xhist, const u16* __restrict__ Wscb,
                  const float* __restrict__ bsc, float* __restrict__ out) {
  __shared__ char smem[SMEM_BYTES];
  const int tau = blockIdx.x + 1;        // 1..160
  const int m0 = blockIdx.y * 64;        // b base
  const int lane = threadIdx.x & 63, wave = threadIdx.x >> 6;
  f32x4 acc[2][2] = {};
  mfma_acc(xhist + (size_t)tau * B_SZ * XROW, XROW, Wscb, XROW, XROW, m0, 0, smem, acc);
  const int wm = (wave >> 1) * 32, wn = (wave & 1) * 32;
  const int col = lane & 15, r4 = (lane >> 4) * 4;
#pragma unroll
  for (int fm = 0; fm < 2; ++fm)
#pragma unroll
    for (int fn = 0; fn < 2; ++fn) {
      int cc = wn + fn * 16 + col;
      if (cc >= V_DIM) continue;
      float bias = bsc[cc];
#pragma unroll
      for (int r = 0; r < 4; ++r) {
        int b = m0 + wm + fm * 16 + r4 + r;
        out[((size_t)b * T_LEN + (tau - 1)) * V_DIM + cc] = acc[fm][fn][r] + bias;
      }
    }
}

// ---------------- host ----------------
extern "C" void kernel_launch(void* const* d_in, const int* in_sizes, int n_in,
                              void* d_out, int out_size, void* d_ws, size_t ws_size,
                              hipStream_t stream) {
  (void)in_sizes; (void)n_in; (void)out_size;

  const float* key    = (const float*)d_in[0];
  const float* value  = (const float*)d_in[1];
  const float* mask   = (const float*)d_in[2];
  const int*   labels = (const int*)d_in[3];
  const float* Wq     = (const float*)d_in[4];
  const float* bq     = (const float*)d_in[5];
  const float* Wsc    = (const float*)d_in[6];
  const float* bsc    = (const float*)d_in[7];
  const float* Emb    = (const float*)d_in[8];
  const float* Wih0   = (const float*)d_in[9];
  const float* Whh0   = (const float*)d_in[10];
  const float* bih0   = (const float*)d_in[11];
  const float* bhh0   = (const float*)d_in[12];
  const float* Wih1   = (const float*)d_in[13];
  const float* Whh1   = (const float*)d_in[14];
  const float* bih1   = (const float*)d_in[15];
  const float* bhh1   = (const float*)d_in[16];
  const float* s0     = (const float*)d_in[17];
  const float* s1     = (const float*)d_in[18];
  const float* cs0    = (const float*)d_in[19];
  const float* cs1    = (const float*)d_in[20];
  float* out = (float*)d_out;

  char* ws = (char*)d_ws;
  size_t off = 0;
  auto alloc = [&](size_t bytes) -> void* {
    void* p = ws + off;
    off += (bytes + 255) & ~(size_t)255;
    return p;
  };
  u16*   h0b    = (u16*)alloc((size_t)B_SZ * H_DIM * 2);
  u16*   h1b    = (u16*)alloc((size_t)B_SZ * H_DIM * 2);
  float* c0     = (float*)alloc((size_t)B_SZ * H_DIM * 4);
  float* c1     = (float*)alloc((size_t)B_SZ * H_DIM * 4);
  u16*   xc0    = (u16*)alloc((size_t)B_SZ * E_DIM * 2);
  float* qbuf   = (float*)alloc((size_t)B_SZ * E_DIM * 4);
  float* pg0    = (float*)alloc((size_t)B_SZ * G4 * 4);
  float* pg1    = (float*)alloc((size_t)B_SZ * G4 * 4);
  u16*   Wih0p  = (u16*)alloc((size_t)G4 * 512 * 2);
  u16*   Whh0p  = (u16*)alloc((size_t)G4 * 512 * 2);
  u16*   Wih1p  = (u16*)alloc((size_t)G4 * 512 * 2);
  u16*   Whh1p  = (u16*)alloc((size_t)G4 * 512 * 2);
  u16*   Wqb    = (u16*)alloc((size_t)E_DIM * 512 * 2);
  u16*   Wscb   = (u16*)alloc((size_t)64 * XROW * 2);
  float* bias0p = (float*)alloc((size_t)G4 * 4);
  float* bias1p = (float*)alloc((size_t)G4 * 4);
  u16*   embs   = (u16*)alloc((size_t)T_LEN * B_SZ * E_DIM * 2);
  int*   cnt    = (int*)alloc(16 * sizeof(int));

  const size_t kv_elems = (size_t)S_LEN * B_SZ * E_DIM;
  const size_t kv_bytes = kv_elems * 2;
  bool bf16kv = (ws_size >= off + 2 * kv_bytes + 1024);
  u16* kb = nullptr; u16* vb = nullptr;
  if (bf16kv) {
    kb = (u16*)alloc(kv_bytes);
    vb = (u16*)alloc(kv_bytes);
  }
  const size_t xh_bytes = (size_t)(T_LEN + 1) * B_SZ * XROW * 2;
  bool defer = (ws_size >= off + xh_bytes + 1024);
  u16* xhist = nullptr;
  if (defer) xhist = (u16*)alloc(xh_bytes);

  init_state<<<(B_SZ * H_DIM) / 256, 256, 0, stream>>>(s0, s1, cs0, cs1, h0b, h1b, c0, c1);
  zero_cnts<<<1, 64, 0, stream>>>(cnt);
  pack_w<<<512, 256, 0, stream>>>(Wih0, Wih0p);
  pack_w<<<512, 256, 0, stream>>>(Whh0, Whh0p);
  pack_w<<<512, 256, 0, stream>>>(Wih1, Wih1p);
  pack_w<<<512, 256, 0, stream>>>(Whh1, Whh1p);
  pack_wq<<<64, 256, 0, stream>>>(Wq, Wqb);
  if (defer) pack_wsc<<<24, 256, 0, stream>>>(Wsc, Wscb);
  pack_bias<<<8, 256, 0, stream>>>(bih0, bhh0, bih1, bhh1, bias0p, bias1p);
  gather_embs<<<(T_LEN * B_SZ * 64 + 255) / 256, 256, 0, stream>>>(Emb, labels, embs);

  if (bf16kv) {
    int n4 = (int)(kv_elems / 4);
    conv_bf16<<<4096, 256, 0, stream>>>(key, kb, n4);
    conv_bf16<<<4096, 256, 0, stream>>>(value, vb, n4);
  }

  dim3 qgrid(E_DIM / 64, B_SZ / 64);
  qgemm<<<qgrid, 256, 0, stream>>>(h1b, Wqb, bq, qbuf);  // q for t=0

  for (int t = 0; t <= T_LEN; ++t) {
    if (bf16kv) {
      if (defer)
        fusedA<u16, true><<<1024, 256, 0, stream>>>(
            kb, vb, mask, qbuf, Wsc, bsc, embs, h0b, h1b,
            Wih0p, Whh0p, Whh1p, xc0, xhist, pg0, pg1, out, t);
      else
        fusedA<u16, false><<<1024, 256, 0, stream>>>(
            kb, vb, mask, qbuf, Wsc, bsc, embs, h0b, h1b,
            Wih0p, Whh0p, Whh1p, xc0, xhist, pg0, pg1, out, t);
    } else {
      if (defer)
        fusedA<float, true><<<1024, 256, 0, stream>>>(
            key, value, mask, qbuf, Wsc, bsc, embs, h0b, h1b,
            Wih0p, Whh0p, Whh1p, xc0, xhist, pg0, pg1, out, t);
      else
        fusedA<float, false><<<1024, 256, 0, stream>>>(
            key, value, mask, qbuf, Wsc, bsc, embs, h0b, h1b,
            Wih0p, Whh0p, Whh1p, xc0, xhist, pg0, pg1, out, t);
    }
    if (t < T_LEN) {
      cells_kernel<<<544, 256, 0, stream>>>(
          xc0, Wih0p, pg0, bias0p, c0,
          Wih1p, pg1, bias1p, c1,
          Wqb, bq, qbuf, h0b, h1b,
          defer ? xhist + (size_t)(t + 1) * B_SZ * XROW : nullptr, cnt, t);
    }
  }

  if (defer) {
    dim3 sgrid(T_LEN, B_SZ / 64);
    score_kernel<<<sgrid, 256, 0, stream>>>(xhist, Wscb, bsc, out);
  }
}

// Round 7
// 13903.532 us; speedup vs baseline: 2.3958x; 2.3958x over previous
//
#include <hip/hip_runtime.h>
#include <hip/hip_bf16.h>
#include <cstdint>
#include <cstddef>

#define S_LEN 512
#define B_SZ  512
#define T_LEN 160
#define E_DIM 256
#define H_DIM 512
#define V_DIM 34
#define G4    2048          // 4*H
#define XROW  768           // [h1 (512) | ctx (256)] history row
#define EPS1  1e-12f
#define BE    (B_SZ * E_DIM)

typedef unsigned short u16;
typedef unsigned char  u8;
typedef __attribute__((ext_vector_type(8))) short bf16x8;
typedef __attribute__((ext_vector_type(4))) float f32x4;

#define SMEM_BYTES 18432    // 2*64*72*2 staging / 64*68*4 C-tile

// ---------------- helpers ----------------
__device__ __forceinline__ float wave_reduce_sum(float v) {
#pragma unroll
  for (int m = 32; m >= 1; m >>= 1) v += __shfl_xor(v, m, 64);
  return v;
}
__device__ __forceinline__ float half_reduce_sum(float v) {  // within 32-lane group
#pragma unroll
  for (int m = 16; m >= 1; m >>= 1) v += __shfl_xor(v, m, 64);
  return v;
}
__device__ __forceinline__ float wave_reduce_max(float v) {
#pragma unroll
  for (int m = 32; m >= 1; m >>= 1) v = fmaxf(v, __shfl_xor(v, m, 64));
  return v;
}
__device__ __forceinline__ float bf2f(u16 u) {
  return __uint_as_float((uint32_t)u << 16);
}
// V loads: fp8 e4m3 (4 bytes -> 4 floats) or fp32 fallback
__device__ __forceinline__ float4 loadV4(const u8* p) {
  uint32_t u = *(const uint32_t*)p;
  float4 r;
  r.x = __builtin_amdgcn_cvt_f32_fp8(u, 0);
  r.y = __builtin_amdgcn_cvt_f32_fp8(u, 1);
  r.z = __builtin_amdgcn_cvt_f32_fp8(u, 2);
  r.w = __builtin_amdgcn_cvt_f32_fp8(u, 3);
  return r;
}
__device__ __forceinline__ float4 loadV4(const float* p) { return *(const float4*)p; }

__device__ __forceinline__ float dot8(const u16* p, const float* q) {
  bf16x8 k8 = *(const bf16x8*)p;
  float acc = 0.f;
#pragma unroll
  for (int i = 0; i < 8; ++i) acc += bf2f((u16)k8[i]) * q[i];
  return acc;
}
__device__ __forceinline__ float dot8(const float* p, const float* q) {
  float4 a = *(const float4*)p, b = *(const float4*)(p + 4);
  return a.x*q[0] + a.y*q[1] + a.z*q[2] + a.w*q[3] +
         b.x*q[4] + b.y*q[5] + b.z*q[6] + b.w*q[7];
}
__device__ __forceinline__ u16 f2bf(float f) {
  uint32_t u = __float_as_uint(f);
  uint32_t r = (u + 0x7FFFu + ((u >> 16) & 1u)) >> 16;
  return (u16)r;
}
__device__ __forceinline__ float sigm(float x) { return 1.f / (1.f + __expf(-x)); }

// ---------------- generic MFMA tile accumulate ----------------
// acc += A[m0..m0+63, 0..klen) . W[n0..n0+63, 0..klen)^T
__device__ __forceinline__ void mfma_acc(const u16* A, int lda, const u16* W, int ldw,
                                         int klen, int m0, int n0, char* smem,
                                         f32x4 (&acc)[2][2]) {
  u16 (*As)[72] = (u16(*)[72])smem;
  u16 (*Ws)[72] = (u16(*)[72])(smem + 64 * 72 * 2);
  const int tid = threadIdx.x;
  const int lane = tid & 63, wave = tid >> 6;
  const int wm = (wave >> 1) * 32, wn = (wave & 1) * 32;
  const int row = lane & 15, kq = (lane >> 4) * 8;

  for (int k0 = 0; k0 < klen; k0 += 64) {
    __syncthreads();
#pragma unroll
    for (int i = tid; i < 512; i += 256) {
      int r = i >> 3, c = (i & 7) * 8;
      *(bf16x8*)&As[r][c] = *(const bf16x8*)(A + (size_t)(m0 + r) * lda + k0 + c);
      *(bf16x8*)&Ws[r][c] = *(const bf16x8*)(W + (size_t)(n0 + r) * ldw + k0 + c);
    }
    __syncthreads();
#pragma unroll
    for (int kk = 0; kk < 64; kk += 32) {
      bf16x8 a0 = *(const bf16x8*)&As[wm + row][kk + kq];
      bf16x8 a1 = *(const bf16x8*)&As[wm + 16 + row][kk + kq];
      bf16x8 b0 = *(const bf16x8*)&Ws[wn + row][kk + kq];
      bf16x8 b1 = *(const bf16x8*)&Ws[wn + 16 + row][kk + kq];
      acc[0][0] = __builtin_amdgcn_mfma_f32_16x16x32_bf16(a0, b0, acc[0][0], 0, 0, 0);
      acc[0][1] = __builtin_amdgcn_mfma_f32_16x16x32_bf16(a0, b1, acc[0][1], 0, 0, 0);
      acc[1][0] = __builtin_amdgcn_mfma_f32_16x16x32_bf16(a1, b0, acc[1][0], 0, 0, 0);
      acc[1][1] = __builtin_amdgcn_mfma_f32_16x16x32_bf16(a1, b1, acc[1][1], 0, 0, 0);
    }
  }
}

// ---------------- init ----------------
__global__ __launch_bounds__(256)
void init_state(const float* __restrict__ s0, const float* __restrict__ s1,
                const float* __restrict__ cs0, const float* __restrict__ cs1,
                u16* __restrict__ h0b, u16* __restrict__ h1b,
                float* __restrict__ c0, float* __restrict__ c1) {
  int idx = blockIdx.x * blockDim.x + threadIdx.x;  // < B*H
  int j = idx & 511;
  h0b[idx] = f2bf(s0[j]);
  h1b[idx] = f2bf(s1[j]);
  c0[idx] = cs0[j];
  c1[idx] = cs1[j];
}

// ---------------- fp32 -> bf16 (K) ----------------
__global__ __launch_bounds__(256)
void conv_bf16(const float* __restrict__ in, u16* __restrict__ outp, int n4) {
  int i = blockIdx.x * blockDim.x + threadIdx.x;
  int stride = gridDim.x * blockDim.x;
  for (; i < n4; i += stride) {
    float4 f = ((const float4*)in)[i];
    ushort4 u;
    u.x = f2bf(f.x); u.y = f2bf(f.y); u.z = f2bf(f.z); u.w = f2bf(f.w);
    ((ushort4*)outp)[i] = u;
  }
}

// ---------------- fp32 -> fp8 e4m3 (V) ----------------
__global__ __launch_bounds__(256)
void conv_fp8(const float* __restrict__ in, u8* __restrict__ outp, int n4) {
  int i = blockIdx.x * blockDim.x + threadIdx.x;
  int stride = gridDim.x * blockDim.x;
  for (; i < n4; i += stride) {
    float4 f = ((const float4*)in)[i];
    uint32_t packed = 0;
    packed = __builtin_amdgcn_cvt_pk_fp8_f32(f.x, f.y, packed, false);
    packed = __builtin_amdgcn_cvt_pk_fp8_f32(f.z, f.w, packed, true);
    ((uint32_t*)outp)[i] = packed;
  }
}

// ---------------- weight packs ----------------
__global__ __launch_bounds__(256)
void pack_w(const float* __restrict__ in, u16* __restrict__ outp) {
  int idx = blockIdx.x * 256 + threadIdx.x;   // 2048*64
  int k = (idx & 63) * 8;
  int np = idx >> 6;
  int j = np >> 2, g = np & 3;
  const float* src = in + ((size_t)(g * 512 + j)) * 512 + k;
  float4 f0 = *(const float4*)src;
  float4 f1 = *(const float4*)(src + 4);
  ushort4 o0, o1;
  o0.x = f2bf(f0.x); o0.y = f2bf(f0.y); o0.z = f2bf(f0.z); o0.w = f2bf(f0.w);
  o1.x = f2bf(f1.x); o1.y = f2bf(f1.y); o1.z = f2bf(f1.z); o1.w = f2bf(f1.w);
  *(ushort4*)(outp + (size_t)np * 512 + k) = o0;
  *(ushort4*)(outp + (size_t)np * 512 + k + 4) = o1;
}

__global__ __launch_bounds__(256)
void pack_wq(const float* __restrict__ in, u16* __restrict__ outp) {
  int idx = blockIdx.x * 256 + threadIdx.x;   // 256*64
  int k = (idx & 63) * 8;
  int e = idx >> 6;
  const float* src = in + (size_t)e * 512 + k;
  float4 f0 = *(const float4*)src;
  float4 f1 = *(const float4*)(src + 4);
  ushort4 o0, o1;
  o0.x = f2bf(f0.x); o0.y = f2bf(f0.y); o0.z = f2bf(f0.z); o0.w = f2bf(f0.w);
  o1.x = f2bf(f1.x); o1.y = f2bf(f1.y); o1.z = f2bf(f1.z); o1.w = f2bf(f1.w);
  *(ushort4*)(outp + (size_t)e * 512 + k) = o0;
  *(ushort4*)(outp + (size_t)e * 512 + k + 4) = o1;
}

// Wscb: 64 rows x 768 cols, rows >= V_DIM zeroed
__global__ __launch_bounds__(256)
void pack_wsc(const float* __restrict__ in, u16* __restrict__ outp) {
  int idx = blockIdx.x * 256 + threadIdx.x;   // 64*96 = 6144
  if (idx >= 64 * 96) return;
  int kq = (idx % 96) * 8;
  int v = idx / 96;
  ushort4 o0 = {0, 0, 0, 0}, o1 = {0, 0, 0, 0};
  if (v < V_DIM) {
    const float* src = in + (size_t)v * XROW + kq;
    float4 f0 = *(const float4*)src;
    float4 f1 = *(const float4*)(src + 4);
    o0.x = f2bf(f0.x); o0.y = f2bf(f0.y); o0.z = f2bf(f0.z); o0.w = f2bf(f0.w);
    o1.x = f2bf(f1.x); o1.y = f2bf(f1.y); o1.z = f2bf(f1.z); o1.w = f2bf(f1.w);
  }
  *(ushort4*)(outp + (size_t)v * XROW + kq) = o0;
  *(ushort4*)(outp + (size_t)v * XROW + kq + 4) = o1;
}

__global__ __launch_bounds__(256)
void pack_bias(const float* bih0, const float* bhh0,
               const float* bih1, const float* bhh1,
               float* bias0p, float* bias1p) {
  int np = blockIdx.x * 256 + threadIdx.x;  // < 2048
  int j = np >> 2, g = np & 3;
  int n = g * 512 + j;
  bias0p[np] = bih0[n] + bhh0[n];
  bias1p[np] = bih1[n] + bhh1[n];
}

// ---------------- pre-gather all embeddings (bf16) ----------------
__global__ __launch_bounds__(256)
void gather_embs(const float* __restrict__ Emb, const int* __restrict__ labels,
                 u16* __restrict__ embs) {
  int idx = blockIdx.x * 256 + threadIdx.x;   // < T*B*64 quads
  if (idx >= T_LEN * B_SZ * 64) return;
  int q = idx & 63;
  int b = (idx >> 6) & 511;
  int t = idx >> 15;
  int lab = labels[(size_t)b * T_LEN + t];
  float4 f = *(const float4*)(Emb + (size_t)lab * E_DIM + q * 4);
  ushort4 o;
  o.x = f2bf(f.x); o.y = f2bf(f.y); o.z = f2bf(f.z); o.w = f2bf(f.w);
  *(ushort4*)(embs + ((size_t)t * B_SZ + b) * E_DIM + q * 4) = o;
}

// ---------------- q GEMM: qbuf(B,256) = h1b(B,512) @ Wqb^T + bq ----------------
__global__ __launch_bounds__(256)
void qgemm(const u16* __restrict__ h1b, const u16* __restrict__ Wqb,
           const float* __restrict__ bq, float* __restrict__ qbuf) {
  __shared__ char smem[SMEM_BYTES];
  const int lane = threadIdx.x & 63, wave = threadIdx.x >> 6;
  const int m0 = blockIdx.y * 64, n0 = blockIdx.x * 64;
  f32x4 acc[2][2] = {};
  mfma_acc(h1b, H_DIM, Wqb, 512, 512, m0, n0, smem, acc);
  const int wm = (wave >> 1) * 32, wn = (wave & 1) * 32;
  const int col = lane & 15, r4 = (lane >> 4) * 4;
#pragma unroll
  for (int fm = 0; fm < 2; ++fm)
#pragma unroll
    for (int fn = 0; fn < 2; ++fn) {
      int cc = n0 + wn + fn * 16 + col;
      float bias = bq[cc];
#pragma unroll
      for (int r = 0; r < 4; ++r) {
        int rr = m0 + wm + fm * 16 + r4 + r;
        qbuf[(size_t)rr * E_DIM + cc] = acc[fm][fn][r] + bias;
      }
    }
}

// ---------------- kernel A: two-phase attend (blocks 0..511) + partial GEMMs --
template <typename KT, typename VT, bool DEFER>
__global__ __launch_bounds__(256)
void fusedA(const KT* __restrict__ key, const VT* __restrict__ value,
            const float* __restrict__ mask, const float* __restrict__ qbuf,
            const float* __restrict__ Wsc, const float* __restrict__ bsc,
            const u16* __restrict__ embs,
            const u16* __restrict__ h0b, const u16* __restrict__ h1b,
            const u16* __restrict__ Wih0p, const u16* __restrict__ Whh0p,
            const u16* __restrict__ Whh1p,
            u16* __restrict__ xc0, u16* __restrict__ xhist,
            float* __restrict__ pg0, float* __restrict__ pg1,
            float* __restrict__ out, int t) {
  __shared__ char smem[SMEM_BYTES];
  const int tid = threadIdx.x;
  const int lane = tid & 63;
  const int wave = tid >> 6;

  if (blockIdx.x >= 512) {
    // -------- partial gate GEMM --------
    if (t >= T_LEN) return;
    int gb = blockIdx.x - 512;
    int m0 = ((gb & 255) >> 5) * 64, n0 = (gb & 31) * 64;
    f32x4 acc[2][2] = {};
    float* pg;
    if (gb < 256) {
      mfma_acc(h0b, H_DIM, Whh0p, 512, 512, m0, n0, smem, acc);
      mfma_acc(embs + (size_t)t * BE, E_DIM, Wih0p, 512, 256, m0, n0, smem, acc);
      pg = pg0;
    } else {
      mfma_acc(h1b, H_DIM, Whh1p, 512, 512, m0, n0, smem, acc);
      pg = pg1;
    }
    const int wm = (wave >> 1) * 32, wn = (wave & 1) * 32;
    const int col = lane & 15, r4 = (lane >> 4) * 4;
#pragma unroll
    for (int fm = 0; fm < 2; ++fm)
#pragma unroll
      for (int fn = 0; fn < 2; ++fn) {
        int cc = n0 + wn + fn * 16 + col;
#pragma unroll
        for (int r = 0; r < 4; ++r) {
          int rr = m0 + wm + fm * 16 + r4 + r;
          pg[(size_t)rr * G4 + cc] = acc[fm][fn][r];
        }
      }
    return;
  }

  // -------- attend (two-phase, independent iterations) --------
  float* qs   = (float*)smem;          // 256
  float* scb  = qs + 256;              // 512
  float* ctxs = scb + 512;             // 256
  float* ctxp = ctxs + 256;            // 4*256
  float* red  = ctxp + 1024;           // 8
  float* h1s  = red + 8;               // 512 (fallback scoring only)
  const int b = blockIdx.x;

  qs[tid] = qbuf[(size_t)b * E_DIM + tid];
  if (!DEFER) {
#pragma unroll
    for (int j = tid; j < H_DIM; j += 256) h1s[j] = bf2f(h1b[(size_t)b * H_DIM + j]);
  }
  __syncthreads();

  // scores: 2 s-rows per wave-iteration, 16B/lane K loads
  {
    int e0 = (lane & 31) << 3;
    float q8[8];
    *(float4*)&q8[0] = *(const float4*)&qs[e0];
    *(float4*)&q8[4] = *(const float4*)&qs[e0 + 4];
    int s = wave * 2 + (lane >> 5);
    const KT* kp = key + (size_t)s * BE + (size_t)b * E_DIM + e0;
#pragma unroll 4
    for (; s < S_LEN; s += 8) {
      float acc = dot8(kp, q8);
      acc = half_reduce_sum(acc);
      if ((lane & 31) == 0) scb[s] = acc;
      kp += (size_t)8 * BE;
    }
  }
  __syncthreads();

  // masked softmax + renorm
  float v0 = scb[tid], v1 = scb[tid + 256];
  {
    float lm = wave_reduce_max(fmaxf(v0, v1));
    if (lane == 0) red[wave] = lm;
  }
  __syncthreads();
  float smax = fmaxf(fmaxf(red[0], red[1]), fmaxf(red[2], red[3]));
  __syncthreads();
  float m0 = mask[(size_t)b * S_LEN + tid];
  float m1 = mask[(size_t)b * S_LEN + tid + 256];
  float p0 = __expf(v0 - smax), p1 = __expf(v1 - smax);
  float pm0 = p0 * m0, pm1 = p1 * m1;
  {
    float sP = wave_reduce_sum(p0 + p1);
    float sPM = wave_reduce_sum(pm0 + pm1);
    if (lane == 0) { red[wave] = sP; red[4 + wave] = sPM; }
  }
  __syncthreads();
  float P  = red[0] + red[1] + red[2] + red[3];
  float PM = red[4] + red[5] + red[6] + red[7];
  float inv = 1.f / fmaxf(PM, EPS1 * P);
  scb[tid] = pm0 * inv;
  scb[tid + 256] = pm1 * inv;
  __syncthreads();

  // ctx: lane owns e-quad, waves split s 4-way; cross-wave reduce in LDS
  {
    float4 cacc = {0.f, 0.f, 0.f, 0.f};
    const VT* vp = value + (size_t)wave * BE + (size_t)b * E_DIM + (lane << 2);
#pragma unroll 8
    for (int s = wave; s < S_LEN; s += 4) {
      float a = scb[s];
      float4 v4 = loadV4(vp);
      cacc.x += a * v4.x; cacc.y += a * v4.y; cacc.z += a * v4.z; cacc.w += a * v4.w;
      vp += (size_t)4 * BE;
    }
    *(float4*)&ctxp[wave * 256 + (lane << 2)] = cacc;
  }
  __syncthreads();
  {
    float ctxe = ctxp[tid] + ctxp[256 + tid] + ctxp[512 + tid] + ctxp[768 + tid];
    ctxs[tid] = ctxe;
    u16 cb = f2bf(ctxe);
    if (t < T_LEN) xc0[(size_t)b * E_DIM + tid] = cb;
    if (DEFER && t >= 1) xhist[((size_t)t * B_SZ + b) * XROW + H_DIM + tid] = cb;
  }

  if (!DEFER) {
    __syncthreads();
    if (t >= 1) {
      for (int v = wave; v < V_DIM; v += 4) {
        const float4* wr = reinterpret_cast<const float4*>(Wsc + (size_t)v * XROW);
        float4 w0 = wr[lane];
        float4 w1 = wr[lane + 64];
        float4 w2 = wr[lane + 128];
        const float* ha = &h1s[4 * lane];
        const float* hb = &h1s[256 + 4 * lane];
        const float* cx = &ctxs[4 * lane];
        float acc = w0.x * ha[0] + w0.y * ha[1] + w0.z * ha[2] + w0.w * ha[3] +
                    w1.x * hb[0] + w1.y * hb[1] + w1.z * hb[2] + w1.w * hb[3] +
                    w2.x * cx[0] + w2.y * cx[1] + w2.z * cx[2] + w2.w * cx[3];
        acc = wave_reduce_sum(acc);
        if (lane == 0) out[((size_t)b * T_LEN + (t - 1)) * V_DIM + v] = acc + bsc[v];
      }
    }
  }
}

// ---------------- cell kernel: x-part GEMM + pg + bias -> gates -> h,c --------
__global__ __launch_bounds__(256)
void cell_kernel(const u16* __restrict__ A, int lda, const u16* __restrict__ Wp,
                 int klen,
                 const float* __restrict__ pg, const float* __restrict__ biasp,
                 float* __restrict__ cbuf,
                 u16* __restrict__ hb, u16* __restrict__ xh) {
  __shared__ char smem[SMEM_BYTES];
  const int tid = threadIdx.x;
  const int lane = tid & 63, wave = tid >> 6;
  const int m0 = blockIdx.y * 64, n0 = blockIdx.x * 64;

  f32x4 acc[2][2] = {};
  mfma_acc(A, lda, Wp, 512, klen, m0, n0, smem, acc);
  __syncthreads();

  float (*Cs)[68] = (float(*)[68])smem;
  const int wm = (wave >> 1) * 32, wn = (wave & 1) * 32;
  const int col = lane & 15, r4 = (lane >> 4) * 4;
#pragma unroll
  for (int fm = 0; fm < 2; ++fm)
#pragma unroll
    for (int fn = 0; fn < 2; ++fn) {
      int cc = wn + fn * 16 + col;
      float bias = biasp[n0 + cc];
#pragma unroll
      for (int r = 0; r < 4; ++r) {
        int rr = wm + fm * 16 + r4 + r;
        Cs[rr][cc] = acc[fm][fn][r] + pg[(size_t)(m0 + rr) * G4 + n0 + cc] + bias;
      }
    }
  __syncthreads();

  // epilogue: 64 m x 16 j per block
  for (int i = tid; i < 1024; i += 256) {
    int m = i >> 4, j = i & 15;
    float4 gv = *(const float4*)&Cs[m][j * 4];   // i,f,g,o
    float ii = sigm(gv.x), ff = sigm(gv.y), tg = tanhf(gv.z), oo = sigm(gv.w);
    int gm = m0 + m, gj = (n0 >> 2) + j;
    size_t cidx = (size_t)gm * H_DIM + gj;
    float cn = ff * cbuf[cidx] + ii * tg;
    float hn = oo * tanhf(cn);
    cbuf[cidx] = cn;
    u16 hv = f2bf(hn);
    hb[cidx] = hv;
    if (xh) xh[(size_t)gm * XROW + gj] = hv;
  }
}

// ---------------- deferred scoring: out = xhist @ Wscb^T + bsc ----------------
__global__ __launch_bounds__(256)
void score_kernel(const u16* __restrict__ xhist, const u16* __restrict__ Wscb,
                  const float* __restrict__ bsc, float* __restrict__ out) {
  __shared__ char smem[SMEM_BYTES];
  const int tau = blockIdx.x + 1;        // 1..160
  const int m0 = blockIdx.y * 64;        // b base
  const int lane = threadIdx.x & 63, wave = threadIdx.x >> 6;
  f32x4 acc[2][2] = {};
  mfma_acc(xhist + (size_t)tau * B_SZ * XROW, XROW, Wscb, XROW, XROW, m0, 0, smem, acc);
  const int wm = (wave >> 1) * 32, wn = (wave & 1) * 32;
  const int col = lane & 15, r4 = (lane >> 4) * 4;
#pragma unroll
  for (int fm = 0; fm < 2; ++fm)
#pragma unroll
    for (int fn = 0; fn < 2; ++fn) {
      int cc = wn + fn * 16 + col;
      if (cc >= V_DIM) continue;
      float bias = bsc[cc];
#pragma unroll
      for (int r = 0; r < 4; ++r) {
        int b = m0 + wm + fm * 16 + r4 + r;
        out[((size_t)b * T_LEN + (tau - 1)) * V_DIM + cc] = acc[fm][fn][r] + bias;
      }
    }
}

// ---------------- host ----------------
extern "C" void kernel_launch(void* const* d_in, const int* in_sizes, int n_in,
                              void* d_out, int out_size, void* d_ws, size_t ws_size,
                              hipStream_t stream) {
  (void)in_sizes; (void)n_in; (void)out_size;

  const float* key    = (const float*)d_in[0];
  const float* value  = (const float*)d_in[1];
  const float* mask   = (const float*)d_in[2];
  const int*   labels = (const int*)d_in[3];
  const float* Wq     = (const float*)d_in[4];
  const float* bq     = (const float*)d_in[5];
  const float* Wsc    = (const float*)d_in[6];
  const float* bsc    = (const float*)d_in[7];
  const float* Emb    = (const float*)d_in[8];
  const float* Wih0   = (const float*)d_in[9];
  const float* Whh0   = (const float*)d_in[10];
  const float* bih0   = (const float*)d_in[11];
  const float* bhh0   = (const float*)d_in[12];
  const float* Wih1   = (const float*)d_in[13];
  const float* Whh1   = (const float*)d_in[14];
  const float* bih1   = (const float*)d_in[15];
  const float* bhh1   = (const float*)d_in[16];
  const float* s0     = (const float*)d_in[17];
  const float* s1     = (const float*)d_in[18];
  const float* cs0    = (const float*)d_in[19];
  const float* cs1    = (const float*)d_in[20];
  float* out = (float*)d_out;

  char* ws = (char*)d_ws;
  size_t off = 0;
  auto alloc = [&](size_t bytes) -> void* {
    void* p = ws + off;
    off += (bytes + 255) & ~(size_t)255;
    return p;
  };
  u16*   h0b    = (u16*)alloc((size_t)B_SZ * H_DIM * 2);
  u16*   h1b    = (u16*)alloc((size_t)B_SZ * H_DIM * 2);
  float* c0     = (float*)alloc((size_t)B_SZ * H_DIM * 4);
  float* c1     = (float*)alloc((size_t)B_SZ * H_DIM * 4);
  u16*   xc0    = (u16*)alloc((size_t)B_SZ * E_DIM * 2);
  float* qbuf   = (float*)alloc((size_t)B_SZ * E_DIM * 4);
  float* pg0    = (float*)alloc((size_t)B_SZ * G4 * 4);
  float* pg1    = (float*)alloc((size_t)B_SZ * G4 * 4);
  u16*   Wih0p  = (u16*)alloc((size_t)G4 * 512 * 2);
  u16*   Whh0p  = (u16*)alloc((size_t)G4 * 512 * 2);
  u16*   Wih1p  = (u16*)alloc((size_t)G4 * 512 * 2);
  u16*   Whh1p  = (u16*)alloc((size_t)G4 * 512 * 2);
  u16*   Wqb    = (u16*)alloc((size_t)E_DIM * 512 * 2);
  u16*   Wscb   = (u16*)alloc((size_t)64 * XROW * 2);
  float* bias0p = (float*)alloc((size_t)G4 * 4);
  float* bias1p = (float*)alloc((size_t)G4 * 4);
  u16*   embs   = (u16*)alloc((size_t)T_LEN * B_SZ * E_DIM * 2);

  const size_t kv_elems = (size_t)S_LEN * B_SZ * E_DIM;
  bool lowkv = (ws_size >= off + kv_elems * 2 + kv_elems + 1024);
  u16* kb = nullptr; u8* vb = nullptr;
  if (lowkv) {
    kb = (u16*)alloc(kv_elems * 2);   // K bf16
    vb = (u8*)alloc(kv_elems);        // V fp8 e4m3
  }
  const size_t xh_bytes = (size_t)(T_LEN + 1) * B_SZ * XROW * 2;
  bool defer = (ws_size >= off + xh_bytes + 1024);
  u16* xhist = nullptr;
  if (defer) xhist = (u16*)alloc(xh_bytes);

  init_state<<<(B_SZ * H_DIM) / 256, 256, 0, stream>>>(s0, s1, cs0, cs1, h0b, h1b, c0, c1);
  pack_w<<<512, 256, 0, stream>>>(Wih0, Wih0p);
  pack_w<<<512, 256, 0, stream>>>(Whh0, Whh0p);
  pack_w<<<512, 256, 0, stream>>>(Wih1, Wih1p);
  pack_w<<<512, 256, 0, stream>>>(Whh1, Whh1p);
  pack_wq<<<64, 256, 0, stream>>>(Wq, Wqb);
  if (defer) pack_wsc<<<24, 256, 0, stream>>>(Wsc, Wscb);
  pack_bias<<<8, 256, 0, stream>>>(bih0, bhh0, bih1, bhh1, bias0p, bias1p);
  gather_embs<<<(T_LEN * B_SZ * 64 + 255) / 256, 256, 0, stream>>>(Emb, labels, embs);

  if (lowkv) {
    int n4 = (int)(kv_elems / 4);
    conv_bf16<<<4096, 256, 0, stream>>>(key, kb, n4);
    conv_fp8<<<4096, 256, 0, stream>>>(value, vb, n4);
  }

  dim3 qgrid(E_DIM / 64, B_SZ / 64);
  qgemm<<<qgrid, 256, 0, stream>>>(h1b, Wqb, bq, qbuf);  // q for t=0

  dim3 cell_grid(G4 / 64, B_SZ / 64);
  for (int t = 0; t <= T_LEN; ++t) {
    if (lowkv) {
      if (defer)
        fusedA<u16, u8, true><<<1024, 256, 0, stream>>>(
            kb, vb, mask, qbuf, Wsc, bsc, embs, h0b, h1b,
            Wih0p, Whh0p, Whh1p, xc0, xhist, pg0, pg1, out, t);
      else
        fusedA<u16, u8, false><<<1024, 256, 0, stream>>>(
            kb, vb, mask, qbuf, Wsc, bsc, embs, h0b, h1b,
            Wih0p, Whh0p, Whh1p, xc0, xhist, pg0, pg1, out, t);
    } else {
      if (defer)
        fusedA<float, float, true><<<1024, 256, 0, stream>>>(
            key, value, mask, qbuf, Wsc, bsc, embs, h0b, h1b,
            Wih0p, Whh0p, Whh1p, xc0, xhist, pg0, pg1, out, t);
      else
        fusedA<float, float, false><<<1024, 256, 0, stream>>>(
            key, value, mask, qbuf, Wsc, bsc, embs, h0b, h1b,
            Wih0p, Whh0p, Whh1p, xc0, xhist, pg0, pg1, out, t);
    }
    if (t < T_LEN) {
      // cell0: ctx part only (K=256, Wih0 cols 256..511) + pg0
      cell_kernel<<<cell_grid, 256, 0, stream>>>(
          xc0, E_DIM, Wih0p + 256, 256, pg0, bias0p, c0, h0b, nullptr);
      // cell1: x = h0 (K=512) + pg1 ; also store h into xhist slot t+1
      cell_kernel<<<cell_grid, 256, 0, stream>>>(
          h0b, H_DIM, Wih1p, 512, pg1, bias1p, c1, h1b,
          defer ? xhist + (size_t)(t + 1) * B_SZ * XROW : nullptr);
      // q for t+1
      qgemm<<<qgrid, 256, 0, stream>>>(h1b, Wqb, bq, qbuf);
    }
  }

  if (defer) {
    dim3 sgrid(T_LEN, B_SZ / 64);
    score_kernel<<<sgrid, 256, 0, stream>>>(xhist, Wscb, bsc, out);
  }
}

// Round 8
// 10858.237 us; speedup vs baseline: 3.0677x; 1.2805x over previous
//
#include <hip/hip_runtime.h>
#include <hip/hip_bf16.h>
#include <cstdint>
#include <cstddef>

#define S_LEN 512
#define B_SZ  512
#define T_LEN 160
#define E_DIM 256
#define H_DIM 512
#define V_DIM 34
#define G4    2048          // 4*H
#define XROW  768           // [h1 (512) | ctx (256)] history row
#define EPS1  1e-12f
#define BE    (B_SZ * E_DIM)

typedef unsigned short u16;
typedef unsigned char  u8;
typedef __attribute__((ext_vector_type(8))) short bf16x8;
typedef __attribute__((ext_vector_type(4))) float f32x4;

#define SMEM_BYTES 18432    // 2*64*72*2 staging / 64*68*4 C-tile

// ---------------- helpers ----------------
__device__ __forceinline__ float wave_reduce_sum(float v) {
#pragma unroll
  for (int m = 32; m >= 1; m >>= 1) v += __shfl_xor(v, m, 64);
  return v;
}
__device__ __forceinline__ float half_reduce_sum(float v) {  // within 32-lane group
#pragma unroll
  for (int m = 16; m >= 1; m >>= 1) v += __shfl_xor(v, m, 64);
  return v;
}
__device__ __forceinline__ float wave_reduce_max(float v) {
#pragma unroll
  for (int m = 32; m >= 1; m >>= 1) v = fmaxf(v, __shfl_xor(v, m, 64));
  return v;
}
__device__ __forceinline__ float bf2f(u16 u) {
  return __uint_as_float((uint32_t)u << 16);
}
// V loads: fp8 e4m3 (4 bytes -> 4 floats) or fp32 fallback
__device__ __forceinline__ float4 loadV4(const u8* p) {
  uint32_t u = *(const uint32_t*)p;
  float4 r;
  r.x = __builtin_amdgcn_cvt_f32_fp8(u, 0);
  r.y = __builtin_amdgcn_cvt_f32_fp8(u, 1);
  r.z = __builtin_amdgcn_cvt_f32_fp8(u, 2);
  r.w = __builtin_amdgcn_cvt_f32_fp8(u, 3);
  return r;
}
__device__ __forceinline__ float4 loadV4(const float* p) { return *(const float4*)p; }

__device__ __forceinline__ float dot8(const u16* p, const float* q) {
  bf16x8 k8 = *(const bf16x8*)p;
  float acc = 0.f;
#pragma unroll
  for (int i = 0; i < 8; ++i) acc += bf2f((u16)k8[i]) * q[i];
  return acc;
}
__device__ __forceinline__ float dot8(const float* p, const float* q) {
  float4 a = *(const float4*)p, b = *(const float4*)(p + 4);
  return a.x*q[0] + a.y*q[1] + a.z*q[2] + a.w*q[3] +
         b.x*q[4] + b.y*q[5] + b.z*q[6] + b.w*q[7];
}
__device__ __forceinline__ u16 f2bf(float f) {
  uint32_t u = __float_as_uint(f);
  uint32_t r = (u + 0x7FFFu + ((u >> 16) & 1u)) >> 16;
  return (u16)r;
}
__device__ __forceinline__ float sigm(float x) { return 1.f / (1.f + __expf(-x)); }

// ---------------- generic MFMA tile accumulate ----------------
// acc += A[m0..m0+63, 0..klen) . W[n0..n0+63, 0..klen)^T
__device__ __forceinline__ void mfma_acc(const u16* A, int lda, const u16* W, int ldw,
                                         int klen, int m0, int n0, char* smem,
                                         f32x4 (&acc)[2][2]) {
  u16 (*As)[72] = (u16(*)[72])smem;
  u16 (*Ws)[72] = (u16(*)[72])(smem + 64 * 72 * 2);
  const int tid = threadIdx.x;
  const int lane = tid & 63, wave = tid >> 6;
  const int wm = (wave >> 1) * 32, wn = (wave & 1) * 32;
  const int row = lane & 15, kq = (lane >> 4) * 8;

  for (int k0 = 0; k0 < klen; k0 += 64) {
    __syncthreads();
#pragma unroll
    for (int i = tid; i < 512; i += 256) {
      int r = i >> 3, c = (i & 7) * 8;
      *(bf16x8*)&As[r][c] = *(const bf16x8*)(A + (size_t)(m0 + r) * lda + k0 + c);
      *(bf16x8*)&Ws[r][c] = *(const bf16x8*)(W + (size_t)(n0 + r) * ldw + k0 + c);
    }
    __syncthreads();
#pragma unroll
    for (int kk = 0; kk < 64; kk += 32) {
      bf16x8 a0 = *(const bf16x8*)&As[wm + row][kk + kq];
      bf16x8 a1 = *(const bf16x8*)&As[wm + 16 + row][kk + kq];
      bf16x8 b0 = *(const bf16x8*)&Ws[wn + row][kk + kq];
      bf16x8 b1 = *(const bf16x8*)&Ws[wn + 16 + row][kk + kq];
      acc[0][0] = __builtin_amdgcn_mfma_f32_16x16x32_bf16(a0, b0, acc[0][0], 0, 0, 0);
      acc[0][1] = __builtin_amdgcn_mfma_f32_16x16x32_bf16(a0, b1, acc[0][1], 0, 0, 0);
      acc[1][0] = __builtin_amdgcn_mfma_f32_16x16x32_bf16(a1, b0, acc[1][0], 0, 0, 0);
      acc[1][1] = __builtin_amdgcn_mfma_f32_16x16x32_bf16(a1, b1, acc[1][1], 0, 0, 0);
    }
  }
}

// ---------------- init ----------------
__global__ __launch_bounds__(256)
void init_state(const float* __restrict__ s0, const float* __restrict__ s1,
                const float* __restrict__ cs0, const float* __restrict__ cs1,
                u16* __restrict__ h0b, u16* __restrict__ h1b,
                float* __restrict__ c0, float* __restrict__ c1) {
  int idx = blockIdx.x * blockDim.x + threadIdx.x;  // < B*H
  int j = idx & 511;
  h0b[idx] = f2bf(s0[j]);
  h1b[idx] = f2bf(s1[j]);
  c0[idx] = cs0[j];
  c1[idx] = cs1[j];
}

// ---------------- fp32 -> bf16 (K) ----------------
__global__ __launch_bounds__(256)
void conv_bf16(const float* __restrict__ in, u16* __restrict__ outp, int n4) {
  int i = blockIdx.x * blockDim.x + threadIdx.x;
  int stride = gridDim.x * blockDim.x;
  for (; i < n4; i += stride) {
    float4 f = ((const float4*)in)[i];
    ushort4 u;
    u.x = f2bf(f.x); u.y = f2bf(f.y); u.z = f2bf(f.z); u.w = f2bf(f.w);
    ((ushort4*)outp)[i] = u;
  }
}

// ---------------- fp32 -> fp8 e4m3 (V) ----------------
__global__ __launch_bounds__(256)
void conv_fp8(const float* __restrict__ in, u8* __restrict__ outp, int n4) {
  int i = blockIdx.x * blockDim.x + threadIdx.x;
  int stride = gridDim.x * blockDim.x;
  for (; i < n4; i += stride) {
    float4 f = ((const float4*)in)[i];
    uint32_t packed = 0;
    packed = __builtin_amdgcn_cvt_pk_fp8_f32(f.x, f.y, packed, false);
    packed = __builtin_amdgcn_cvt_pk_fp8_f32(f.z, f.w, packed, true);
    ((uint32_t*)outp)[i] = packed;
  }
}

// ---------------- weight packs ----------------
__global__ __launch_bounds__(256)
void pack_w(const float* __restrict__ in, u16* __restrict__ outp) {
  int idx = blockIdx.x * 256 + threadIdx.x;   // 2048*64
  int k = (idx & 63) * 8;
  int np = idx >> 6;
  int j = np >> 2, g = np & 3;
  const float* src = in + ((size_t)(g * 512 + j)) * 512 + k;
  float4 f0 = *(const float4*)src;
  float4 f1 = *(const float4*)(src + 4);
  ushort4 o0, o1;
  o0.x = f2bf(f0.x); o0.y = f2bf(f0.y); o0.z = f2bf(f0.z); o0.w = f2bf(f0.w);
  o1.x = f2bf(f1.x); o1.y = f2bf(f1.y); o1.z = f2bf(f1.z); o1.w = f2bf(f1.w);
  *(ushort4*)(outp + (size_t)np * 512 + k) = o0;
  *(ushort4*)(outp + (size_t)np * 512 + k + 4) = o1;
}

__global__ __launch_bounds__(256)
void pack_wq(const float* __restrict__ in, u16* __restrict__ outp) {
  int idx = blockIdx.x * 256 + threadIdx.x;   // 256*64
  int k = (idx & 63) * 8;
  int e = idx >> 6;
  const float* src = in + (size_t)e * 512 + k;
  float4 f0 = *(const float4*)src;
  float4 f1 = *(const float4*)(src + 4);
  ushort4 o0, o1;
  o0.x = f2bf(f0.x); o0.y = f2bf(f0.y); o0.z = f2bf(f0.z); o0.w = f2bf(f0.w);
  o1.x = f2bf(f1.x); o1.y = f2bf(f1.y); o1.z = f2bf(f1.z); o1.w = f2bf(f1.w);
  *(ushort4*)(outp + (size_t)e * 512 + k) = o0;
  *(ushort4*)(outp + (size_t)e * 512 + k + 4) = o1;
}

// Wscb: 64 rows x 768 cols, rows >= V_DIM zeroed
__global__ __launch_bounds__(256)
void pack_wsc(const float* __restrict__ in, u16* __restrict__ outp) {
  int idx = blockIdx.x * 256 + threadIdx.x;   // 64*96 = 6144
  if (idx >= 64 * 96) return;
  int kq = (idx % 96) * 8;
  int v = idx / 96;
  ushort4 o0 = {0, 0, 0, 0}, o1 = {0, 0, 0, 0};
  if (v < V_DIM) {
    const float* src = in + (size_t)v * XROW + kq;
    float4 f0 = *(const float4*)src;
    float4 f1 = *(const float4*)(src + 4);
    o0.x = f2bf(f0.x); o0.y = f2bf(f0.y); o0.z = f2bf(f0.z); o0.w = f2bf(f0.w);
    o1.x = f2bf(f1.x); o1.y = f2bf(f1.y); o1.z = f2bf(f1.z); o1.w = f2bf(f1.w);
  }
  *(ushort4*)(outp + (size_t)v * XROW + kq) = o0;
  *(ushort4*)(outp + (size_t)v * XROW + kq + 4) = o1;
}

__global__ __launch_bounds__(256)
void pack_bias(const float* bih0, const float* bhh0,
               const float* bih1, const float* bhh1,
               float* bias0p, float* bias1p) {
  int np = blockIdx.x * 256 + threadIdx.x;  // < 2048
  int j = np >> 2, g = np & 3;
  int n = g * 512 + j;
  bias0p[np] = bih0[n] + bhh0[n];
  bias1p[np] = bih1[n] + bhh1[n];
}

// ---------------- pre-gather all embeddings (bf16) ----------------
__global__ __launch_bounds__(256)
void gather_embs(const float* __restrict__ Emb, const int* __restrict__ labels,
                 u16* __restrict__ embs) {
  int idx = blockIdx.x * 256 + threadIdx.x;   // < T*B*64 quads
  if (idx >= T_LEN * B_SZ * 64) return;
  int q = idx & 63;
  int b = (idx >> 6) & 511;
  int t = idx >> 15;
  int lab = labels[(size_t)b * T_LEN + t];
  float4 f = *(const float4*)(Emb + (size_t)lab * E_DIM + q * 4);
  ushort4 o;
  o.x = f2bf(f.x); o.y = f2bf(f.y); o.z = f2bf(f.z); o.w = f2bf(f.w);
  *(ushort4*)(embs + ((size_t)t * B_SZ + b) * E_DIM + q * 4) = o;
}

// ---------------- q GEMM: qbuf(B,256) = h1b(B,512) @ Wqb^T + bq ----------------
__global__ __launch_bounds__(256)
void qgemm(const u16* __restrict__ h1b, const u16* __restrict__ Wqb,
           const float* __restrict__ bq, float* __restrict__ qbuf) {
  __shared__ char smem[SMEM_BYTES];
  const int lane = threadIdx.x & 63, wave = threadIdx.x >> 6;
  const int m0 = blockIdx.y * 64, n0 = blockIdx.x * 64;
  f32x4 acc[2][2] = {};
  mfma_acc(h1b, H_DIM, Wqb, 512, 512, m0, n0, smem, acc);
  const int wm = (wave >> 1) * 32, wn = (wave & 1) * 32;
  const int col = lane & 15, r4 = (lane >> 4) * 4;
#pragma unroll
  for (int fm = 0; fm < 2; ++fm)
#pragma unroll
    for (int fn = 0; fn < 2; ++fn) {
      int cc = n0 + wn + fn * 16 + col;
      float bias = bq[cc];
#pragma unroll
      for (int r = 0; r < 4; ++r) {
        int rr = m0 + wm + fm * 16 + r4 + r;
        qbuf[(size_t)rr * E_DIM + cc] = acc[fm][fn][r] + bias;
      }
    }
}

// ---------------- kernel A: two-phase attend (blocks 0..511) + partial GEMMs --
template <typename KT, typename VT, bool DEFER>
__global__ __launch_bounds__(256)
void fusedA(const KT* __restrict__ key, const VT* __restrict__ value,
            const float* __restrict__ mask, const float* __restrict__ qbuf,
            const float* __restrict__ Wsc, const float* __restrict__ bsc,
            const u16* __restrict__ embs,
            const u16* __restrict__ h0b, const u16* __restrict__ h1b,
            const u16* __restrict__ Wih0p, const u16* __restrict__ Whh0p,
            const u16* __restrict__ Whh1p,
            u16* __restrict__ xc0, u16* __restrict__ xhist,
            float* __restrict__ pg0, float* __restrict__ pg1,
            float* __restrict__ out, int t) {
  __shared__ char smem[SMEM_BYTES];
  const int tid = threadIdx.x;
  const int lane = tid & 63;
  const int wave = tid >> 6;

  if (blockIdx.x >= 512) {
    // -------- partial gate GEMM --------
    if (t >= T_LEN) return;
    int gb = blockIdx.x - 512;
    int m0 = ((gb & 255) >> 5) * 64, n0 = (gb & 31) * 64;
    f32x4 acc[2][2] = {};
    float* pg;
    if (gb < 256) {
      mfma_acc(h0b, H_DIM, Whh0p, 512, 512, m0, n0, smem, acc);
      mfma_acc(embs + (size_t)t * BE, E_DIM, Wih0p, 512, 256, m0, n0, smem, acc);
      pg = pg0;
    } else {
      mfma_acc(h1b, H_DIM, Whh1p, 512, 512, m0, n0, smem, acc);
      pg = pg1;
    }
    const int wm = (wave >> 1) * 32, wn = (wave & 1) * 32;
    const int col = lane & 15, r4 = (lane >> 4) * 4;
#pragma unroll
    for (int fm = 0; fm < 2; ++fm)
#pragma unroll
      for (int fn = 0; fn < 2; ++fn) {
        int cc = n0 + wn + fn * 16 + col;
#pragma unroll
        for (int r = 0; r < 4; ++r) {
          int rr = m0 + wm + fm * 16 + r4 + r;
          pg[(size_t)rr * G4 + cc] = acc[fm][fn][r];
        }
      }
    return;
  }

  // -------- attend (two-phase, independent iterations) --------
  float* qs   = (float*)smem;          // 256
  float* scb  = qs + 256;              // 512
  float* ctxs = scb + 512;             // 256
  float* ctxp = ctxs + 256;            // 4*256
  float* red  = ctxp + 1024;           // 8
  float* h1s  = red + 8;               // 512 (fallback scoring only)
  const int b = blockIdx.x;

  qs[tid] = qbuf[(size_t)b * E_DIM + tid];
  if (!DEFER) {
#pragma unroll
    for (int j = tid; j < H_DIM; j += 256) h1s[j] = bf2f(h1b[(size_t)b * H_DIM + j]);
  }
  __syncthreads();

  // scores: per iter each 32-lane half-group computes 2 consecutive s-rows
  // (2x16B loads in flight per lane); per-row arithmetic identical to the
  // reference dot8 + half_reduce pattern -> bit-identical scb[] values.
  {
    int e0 = (lane & 31) << 3;
    float q8[8];
    *(float4*)&q8[0] = *(const float4*)&qs[e0];
    *(float4*)&q8[4] = *(const float4*)&qs[e0 + 4];
    int s = wave * 4 + (lane >> 5) * 2;      // rows s, s+1 this iter
    const KT* kp = key + (size_t)s * BE + (size_t)b * E_DIM + e0;
#pragma unroll 4
    for (int it = 0; it < 32; ++it) {
      float a0 = dot8(kp, q8);
      float a1 = dot8(kp + BE, q8);
      a0 = half_reduce_sum(a0);
      a1 = half_reduce_sum(a1);
      if ((lane & 31) == 0) { scb[s] = a0; scb[s + 1] = a1; }
      s += 16;
      kp += (size_t)16 * BE;
    }
  }
  __syncthreads();

  // masked softmax + renorm
  float v0 = scb[tid], v1 = scb[tid + 256];
  {
    float lm = wave_reduce_max(fmaxf(v0, v1));
    if (lane == 0) red[wave] = lm;
  }
  __syncthreads();
  float smax = fmaxf(fmaxf(red[0], red[1]), fmaxf(red[2], red[3]));
  __syncthreads();
  float m0 = mask[(size_t)b * S_LEN + tid];
  float m1 = mask[(size_t)b * S_LEN + tid + 256];
  float p0 = __expf(v0 - smax), p1 = __expf(v1 - smax);
  float pm0 = p0 * m0, pm1 = p1 * m1;
  {
    float sP = wave_reduce_sum(p0 + p1);
    float sPM = wave_reduce_sum(pm0 + pm1);
    if (lane == 0) { red[wave] = sP; red[4 + wave] = sPM; }
  }
  __syncthreads();
  float P  = red[0] + red[1] + red[2] + red[3];
  float PM = red[4] + red[5] + red[6] + red[7];
  float inv = 1.f / fmaxf(PM, EPS1 * P);
  scb[tid] = pm0 * inv;
  scb[tid + 256] = pm1 * inv;
  __syncthreads();

  // ctx: lane owns e-quad, waves split s 4-way; cross-wave reduce in LDS
  // (same s-order per wave as before -> identical fp accumulation order)
  {
    float4 cacc = {0.f, 0.f, 0.f, 0.f};
    const VT* vp = value + (size_t)wave * BE + (size_t)b * E_DIM + (lane << 2);
#pragma unroll 16
    for (int s = wave; s < S_LEN; s += 4) {
      float a = scb[s];
      float4 v4 = loadV4(vp);
      cacc.x += a * v4.x; cacc.y += a * v4.y; cacc.z += a * v4.z; cacc.w += a * v4.w;
      vp += (size_t)4 * BE;
    }
    *(float4*)&ctxp[wave * 256 + (lane << 2)] = cacc;
  }
  __syncthreads();
  {
    float ctxe = ctxp[tid] + ctxp[256 + tid] + ctxp[512 + tid] + ctxp[768 + tid];
    ctxs[tid] = ctxe;
    u16 cb = f2bf(ctxe);
    if (t < T_LEN) xc0[(size_t)b * E_DIM + tid] = cb;
    if (DEFER && t >= 1) xhist[((size_t)t * B_SZ + b) * XROW + H_DIM + tid] = cb;
  }

  if (!DEFER) {
    __syncthreads();
    if (t >= 1) {
      for (int v = wave; v < V_DIM; v += 4) {
        const float4* wr = reinterpret_cast<const float4*>(Wsc + (size_t)v * XROW);
        float4 w0 = wr[lane];
        float4 w1 = wr[lane + 64];
        float4 w2 = wr[lane + 128];
        const float* ha = &h1s[4 * lane];
        const float* hb = &h1s[256 + 4 * lane];
        const float* cx = &ctxs[4 * lane];
        float acc = w0.x * ha[0] + w0.y * ha[1] + w0.z * ha[2] + w0.w * ha[3] +
                    w1.x * hb[0] + w1.y * hb[1] + w1.z * hb[2] + w1.w * hb[3] +
                    w2.x * cx[0] + w2.y * cx[1] + w2.z * cx[2] + w2.w * cx[3];
        acc = wave_reduce_sum(acc);
        if (lane == 0) out[((size_t)b * T_LEN + (t - 1)) * V_DIM + v] = acc + bsc[v];
      }
    }
  }
}

// ---------------- cell kernel: x-part GEMM + pg + bias -> gates -> h,c --------
__global__ __launch_bounds__(256)
void cell_kernel(const u16* __restrict__ A, int lda, const u16* __restrict__ Wp,
                 int klen,
                 const float* __restrict__ pg, const float* __restrict__ biasp,
                 float* __restrict__ cbuf,
                 u16* __restrict__ hb, u16* __restrict__ xh) {
  __shared__ char smem[SMEM_BYTES];
  const int tid = threadIdx.x;
  const int lane = tid & 63, wave = tid >> 6;
  const int m0 = blockIdx.y * 64, n0 = blockIdx.x * 64;

  f32x4 acc[2][2] = {};
  mfma_acc(A, lda, Wp, 512, klen, m0, n0, smem, acc);
  __syncthreads();

  float (*Cs)[68] = (float(*)[68])smem;
  const int wm = (wave >> 1) * 32, wn = (wave & 1) * 32;
  const int col = lane & 15, r4 = (lane >> 4) * 4;
#pragma unroll
  for (int fm = 0; fm < 2; ++fm)
#pragma unroll
    for (int fn = 0; fn < 2; ++fn) {
      int cc = wn + fn * 16 + col;
      float bias = biasp[n0 + cc];
#pragma unroll
      for (int r = 0; r < 4; ++r) {
        int rr = wm + fm * 16 + r4 + r;
        Cs[rr][cc] = acc[fm][fn][r] + pg[(size_t)(m0 + rr) * G4 + n0 + cc] + bias;
      }
    }
  __syncthreads();

  // epilogue: 64 m x 16 j per block
  for (int i = tid; i < 1024; i += 256) {
    int m = i >> 4, j = i & 15;
    float4 gv = *(const float4*)&Cs[m][j * 4];   // i,f,g,o
    float ii = sigm(gv.x), ff = sigm(gv.y), tg = tanhf(gv.z), oo = sigm(gv.w);
    int gm = m0 + m, gj = (n0 >> 2) + j;
    size_t cidx = (size_t)gm * H_DIM + gj;
    float cn = ff * cbuf[cidx] + ii * tg;
    float hn = oo * tanhf(cn);
    cbuf[cidx] = cn;
    u16 hv = f2bf(hn);
    hb[cidx] = hv;
    if (xh) xh[(size_t)gm * XROW + gj] = hv;
  }
}

// ---------------- deferred scoring: out = xhist @ Wscb^T + bsc ----------------
__global__ __launch_bounds__(256)
void score_kernel(const u16* __restrict__ xhist, const u16* __restrict__ Wscb,
                  const float* __restrict__ bsc, float* __restrict__ out) {
  __shared__ char smem[SMEM_BYTES];
  const int tau = blockIdx.x + 1;        // 1..160
  const int m0 = blockIdx.y * 64;        // b base
  const int lane = threadIdx.x & 63, wave = threadIdx.x >> 6;
  f32x4 acc[2][2] = {};
  mfma_acc(xhist + (size_t)tau * B_SZ * XROW, XROW, Wscb, XROW, XROW, m0, 0, smem, acc);
  const int wm = (wave >> 1) * 32, wn = (wave & 1) * 32;
  const int col = lane & 15, r4 = (lane >> 4) * 4;
#pragma unroll
  for (int fm = 0; fm < 2; ++fm)
#pragma unroll
    for (int fn = 0; fn < 2; ++fn) {
      int cc = wn + fn * 16 + col;
      if (cc >= V_DIM) continue;
      float bias = bsc[cc];
#pragma unroll
      for (int r = 0; r < 4; ++r) {
        int b = m0 + wm + fm * 16 + r4 + r;
        out[((size_t)b * T_LEN + (tau - 1)) * V_DIM + cc] = acc[fm][fn][r] + bias;
      }
    }
}

// ---------------- host ----------------
extern "C" void kernel_launch(void* const* d_in, const int* in_sizes, int n_in,
                              void* d_out, int out_size, void* d_ws, size_t ws_size,
                              hipStream_t stream) {
  (void)in_sizes; (void)n_in; (void)out_size;

  const float* key    = (const float*)d_in[0];
  const float* value  = (const float*)d_in[1];
  const float* mask   = (const float*)d_in[2];
  const int*   labels = (const int*)d_in[3];
  const float* Wq     = (const float*)d_in[4];
  const float* bq     = (const float*)d_in[5];
  const float* Wsc    = (const float*)d_in[6];
  const float* bsc    = (const float*)d_in[7];
  const float* Emb    = (const float*)d_in[8];
  const float* Wih0   = (const float*)d_in[9];
  const float* Whh0   = (const float*)d_in[10];
  const float* bih0   = (const float*)d_in[11];
  const float* bhh0   = (const float*)d_in[12];
  const float* Wih1   = (const float*)d_in[13];
  const float* Whh1   = (const float*)d_in[14];
  const float* bih1   = (const float*)d_in[15];
  const float* bhh1   = (const float*)d_in[16];
  const float* s0     = (const float*)d_in[17];
  const float* s1     = (const float*)d_in[18];
  const float* cs0    = (const float*)d_in[19];
  const float* cs1    = (const float*)d_in[20];
  float* out = (float*)d_out;

  char* ws = (char*)d_ws;
  size_t off = 0;
  auto alloc = [&](size_t bytes) -> void* {
    void* p = ws + off;
    off += (bytes + 255) & ~(size_t)255;
    return p;
  };
  u16*   h0b    = (u16*)alloc((size_t)B_SZ * H_DIM * 2);
  u16*   h1b    = (u16*)alloc((size_t)B_SZ * H_DIM * 2);
  float* c0     = (float*)alloc((size_t)B_SZ * H_DIM * 4);
  float* c1     = (float*)alloc((size_t)B_SZ * H_DIM * 4);
  u16*   xc0    = (u16*)alloc((size_t)B_SZ * E_DIM * 2);
  float* qbuf   = (float*)alloc((size_t)B_SZ * E_DIM * 4);
  float* pg0    = (float*)alloc((size_t)B_SZ * G4 * 4);
  float* pg1    = (float*)alloc((size_t)B_SZ * G4 * 4);
  u16*   Wih0p  = (u16*)alloc((size_t)G4 * 512 * 2);
  u16*   Whh0p  = (u16*)alloc((size_t)G4 * 512 * 2);
  u16*   Wih1p  = (u16*)alloc((size_t)G4 * 512 * 2);
  u16*   Whh1p  = (u16*)alloc((size_t)G4 * 512 * 2);
  u16*   Wqb    = (u16*)alloc((size_t)E_DIM * 512 * 2);
  u16*   Wscb   = (u16*)alloc((size_t)64 * XROW * 2);
  float* bias0p = (float*)alloc((size_t)G4 * 4);
  float* bias1p = (float*)alloc((size_t)G4 * 4);
  u16*   embs   = (u16*)alloc((size_t)T_LEN * B_SZ * E_DIM * 2);

  const size_t kv_elems = (size_t)S_LEN * B_SZ * E_DIM;
  bool lowkv = (ws_size >= off + kv_elems * 2 + kv_elems + 1024);
  u16* kb = nullptr; u8* vb = nullptr;
  if (lowkv) {
    kb = (u16*)alloc(kv_elems * 2);   // K bf16
    vb = (u8*)alloc(kv_elems);        // V fp8 e4m3
  }
  const size_t xh_bytes = (size_t)(T_LEN + 1) * B_SZ * XROW * 2;
  bool defer = (ws_size >= off + xh_bytes + 1024);
  u16* xhist = nullptr;
  if (defer) xhist = (u16*)alloc(xh_bytes);

  init_state<<<(B_SZ * H_DIM) / 256, 256, 0, stream>>>(s0, s1, cs0, cs1, h0b, h1b, c0, c1);
  pack_w<<<512, 256, 0, stream>>>(Wih0, Wih0p);
  pack_w<<<512, 256, 0, stream>>>(Whh0, Whh0p);
  pack_w<<<512, 256, 0, stream>>>(Wih1, Wih1p);
  pack_w<<<512, 256, 0, stream>>>(Whh1, Whh1p);
  pack_wq<<<64, 256, 0, stream>>>(Wq, Wqb);
  if (defer) pack_wsc<<<24, 256, 0, stream>>>(Wsc, Wscb);
  pack_bias<<<8, 256, 0, stream>>>(bih0, bhh0, bih1, bhh1, bias0p, bias1p);
  gather_embs<<<(T_LEN * B_SZ * 64 + 255) / 256, 256, 0, stream>>>(Emb, labels, embs);

  if (lowkv) {
    int n4 = (int)(kv_elems / 4);
    conv_bf16<<<4096, 256, 0, stream>>>(key, kb, n4);
    conv_fp8<<<4096, 256, 0, stream>>>(value, vb, n4);
  }

  dim3 qgrid(E_DIM / 64, B_SZ / 64);
  qgemm<<<qgrid, 256, 0, stream>>>(h1b, Wqb, bq, qbuf);  // q for t=0

  dim3 cell_grid(G4 / 64, B_SZ / 64);
  for (int t = 0; t <= T_LEN; ++t) {
    if (lowkv) {
      if (defer)
        fusedA<u16, u8, true><<<1024, 256, 0, stream>>>(
            kb, vb, mask, qbuf, Wsc, bsc, embs, h0b, h1b,
            Wih0p, Whh0p, Whh1p, xc0, xhist, pg0, pg1, out, t);
      else
        fusedA<u16, u8, false><<<1024, 256, 0, stream>>>(
            kb, vb, mask, qbuf, Wsc, bsc, embs, h0b, h1b,
            Wih0p, Whh0p, Whh1p, xc0, xhist, pg0, pg1, out, t);
    } else {
      if (defer)
        fusedA<float, float, true><<<1024, 256, 0, stream>>>(
            key, value, mask, qbuf, Wsc, bsc, embs, h0b, h1b,
            Wih0p, Whh0p, Whh1p, xc0, xhist, pg0, pg1, out, t);
      else
        fusedA<float, float, false><<<1024, 256, 0, stream>>>(
            key, value, mask, qbuf, Wsc, bsc, embs, h0b, h1b,
            Wih0p, Whh0p, Whh1p, xc0, xhist, pg0, pg1, out, t);
    }
    if (t < T_LEN) {
      // cell0: ctx part only (K=256, Wih0 cols 256..511) + pg0
      cell_kernel<<<cell_grid, 256, 0, stream>>>(
          xc0, E_DIM, Wih0p + 256, 256, pg0, bias0p, c0, h0b, nullptr);
      // cell1: x = h0 (K=512) + pg1 ; also store h into xhist slot t+1
      cell_kernel<<<cell_grid, 256, 0, stream>>>(
          h0b, H_DIM, Wih1p, 512, pg1, bias1p, c1, h1b,
          defer ? xhist + (size_t)(t + 1) * B_SZ * XROW : nullptr);
      // q for t+1
      qgemm<<<qgrid, 256, 0, stream>>>(h1b, Wqb, bq, qbuf);
    }
  }

  if (defer) {
    dim3 sgrid(T_LEN, B_SZ / 64);
    score_kernel<<<sgrid, 256, 0, stream>>>(xhist, Wscb, bsc, out);
  }
}